// Round 2
// baseline (13028.334 us; speedup 1.0000x reference)
//
#include <hip/hip_runtime.h>
#include <hip/hip_bf16.h>

typedef unsigned short ushort_t;
typedef __attribute__((ext_vector_type(8))) short bf16x8;
typedef __attribute__((ext_vector_type(4))) float f32x4;

#define T_DIM 128
#define B_DIM 512
#define DIN 512
#define H_DIM 512
#define DM 256
#define HYP 256
#define L_DIM 100

__device__ __forceinline__ float bf2f(ushort_t u) {
    return __uint_as_float(((unsigned)u) << 16);
}
__device__ __forceinline__ ushort_t f2bf(float f) {
    unsigned u = __float_as_uint(f);
    unsigned r = (u + 0x7fffu + ((u >> 16) & 1u)) >> 16;
    return (ushort_t)r;
}
__device__ __forceinline__ float sigmoidf_(float x) {
    return 1.0f / (1.0f + __expf(-x));
}
// NaN/inf scrub + clamp: keeps garbage-world values finite so failures are diagnosable.
__device__ __forceinline__ float fixf(float v) {
    if (!(v == v)) return 0.f;
    return fminf(fmaxf(v, -65504.f), 65504.f);
}

// ---------------------------------------------------------------------------
// dtype detector: valid bf16 never has exponent 0xFF; f32 read as ushorts does
// (~0.4% of low halves). Single block -> flag: 1 = inputs are f32, 0 = bf16.
// ---------------------------------------------------------------------------
__global__ __launch_bounds__(256) void detect_kernel(const ushort_t* x, int nscan, int* flag) {
    __shared__ int found;
    if (threadIdx.x == 0) found = 0;
    __syncthreads();
    int f = 0;
    for (int i = threadIdx.x; i < nscan; i += 256) {
        unsigned u = x[i];
        if ((u & 0x7F80u) == 0x7F80u) f = 1;
    }
    if (f) atomicOr(&found, 1);
    __syncthreads();
    if (threadIdx.x == 0) *flag = found;
}

// ---------------------------------------------------------------------------
// Ingest: convert all 21 float tensors to canonical bf16 copies in workspace.
// ---------------------------------------------------------------------------
struct IngestP {
    const void* src[21];
    ushort_t* dst[21];
    int n[21];
    long total;
    const int* flag;
};

__global__ __launch_bounds__(256) void ingest_all(IngestP p) {
    int f = *p.flag;
    long idx0 = (long)blockIdx.x * 256 + threadIdx.x;
    long stride = (long)gridDim.x * 256;
    for (long idx = idx0; idx < p.total; idx += stride) {
        long r = idx;
#pragma unroll 1
        for (int t = 0; t < 21; t++) {
            if (r < p.n[t]) {
                p.dst[t][r] = f ? f2bf(((const float*)p.src[t])[r])
                               : ((const ushort_t*)p.src[t])[r];
                break;
            }
            r -= p.n[t];
        }
    }
}

// zero the two h_hat outputs (element offsets [34078720, 34340864)), flag-aware width
__global__ __launch_bounds__(256) void zero_hhat(void* outbase, const int* flagp) {
    long i = 34078720 + (long)blockIdx.x * 256 + threadIdx.x;
    if (*flagp) ((float*)outbase)[i] = 0.f;
    else        ((ushort_t*)outbase)[i] = 0;
}

// ---------------------------------------------------------------------------
// Generic bf16 GEMM: out[r, n] = sum_k A(r,k) * W(n,k)   (A row-major, W row-major N x K)
// Block tile 128x128, BK=32, 4 waves (2x2 of 64x64), v_mfma_f32_16x16x32_bf16.
// LDS rows padded to 40 bf16 (80B) -> 2-way bank alias only (free per m136).
// ---------------------------------------------------------------------------
struct GP {
    const ushort_t* A1; const ushort_t* A2;
    const ushort_t* W1; const ushort_t* W2;
    long lda1, lda2, ldw1, ldw2;
    int K1, wc1, wc2, Nsplit, K, mode;
    const ushort_t* bias; ushort_t* outb; long ldo;          // mode 0
    const ushort_t* pre; ushort_t* merged; float* wh;        // mode 1
    float* outf; const float* fbias;                         // mode 2
};

__global__ __launch_bounds__(256) void gemm_bt(GP g) {
    __shared__ __attribute__((aligned(16))) ushort_t As[128 * 40];
    __shared__ __attribute__((aligned(16))) ushort_t Bs[128 * 40];
    int tid  = threadIdx.x;
    int lane = tid & 63, wave = tid >> 6;
    int wm = (wave & 1) * 64, wn = (wave >> 1) * 64;
    int ml = lane & 15, quad = lane >> 4;
    long rowA0 = (long)blockIdx.x * 128;
    long rowW0 = (long)blockIdx.y * 128;
    int arow = tid >> 2, acol = (tid & 3) * 8;

    f32x4 acc[4][4];
#pragma unroll
    for (int i = 0; i < 4; i++)
#pragma unroll
        for (int j = 0; j < 4; j++) acc[i][j] = (f32x4){0.f, 0.f, 0.f, 0.f};

    for (int k0 = 0; k0 < g.K; k0 += 32) {
        uint4 av[2], wv[2];
#pragma unroll
        for (int s = 0; s < 2; s++) {
            int r = arow + s * 64;
            int k = k0 + acol;
            const ushort_t* asrc = (k < g.K1)
                ? g.A1 + (rowA0 + r) * g.lda1 + k
                : g.A2 + (rowA0 + r) * g.lda2 + (k - g.K1);
            av[s] = *(const uint4*)asrc;
            long n = rowW0 + r;
            const ushort_t* wsrc = (n < g.Nsplit)
                ? g.W1 + n * g.ldw1 + g.wc1 + k
                : g.W2 + (n - g.Nsplit) * g.ldw2 + g.wc2 + k;
            wv[s] = *(const uint4*)wsrc;
        }
        __syncthreads();
#pragma unroll
        for (int s = 0; s < 2; s++) {
            *(uint4*)&As[(arow + s * 64) * 40 + acol] = av[s];
            *(uint4*)&Bs[(arow + s * 64) * 40 + acol] = wv[s];
        }
        __syncthreads();
        bf16x8 af[4], bfm[4];
#pragma unroll
        for (int i = 0; i < 4; i++)
            af[i] = *(const bf16x8*)&As[(wm + i * 16 + ml) * 40 + quad * 8];
#pragma unroll
        for (int j = 0; j < 4; j++)
            bfm[j] = *(const bf16x8*)&Bs[(wn + j * 16 + ml) * 40 + quad * 8];
#pragma unroll
        for (int i = 0; i < 4; i++)
#pragma unroll
            for (int j = 0; j < 4; j++)
                acc[i][j] = __builtin_amdgcn_mfma_f32_16x16x32_bf16(af[i], bfm[j], acc[i][j], 0, 0, 0);
    }

#pragma unroll
    for (int i = 0; i < 4; i++) {
#pragma unroll
        for (int j = 0; j < 4; j++) {
            long rb = rowA0 + wm + i * 16 + quad * 4;
            long cn = rowW0 + wn + j * 16 + ml;
#pragma unroll
            for (int r = 0; r < 4; r++) {
                float v = acc[i][j][r];
                long rr = rb + r;
                if (g.mode == 0) {
                    if (g.bias) v += bf2f(g.bias[cn]);
                    g.outb[rr * g.ldo + cn] = f2bf(v);
                } else if (g.mode == 1) {
                    if (cn < 256) {
                        v += bf2f(g.pre[rr * 256 + cn]);
                        v = v > 0.f ? v : 0.f;
                        g.merged[rr * 256 + cn] = f2bf(v);
                    } else {
                        g.wh[rr * 2048 + (cn - 256)] = v;
                    }
                } else {
                    g.outf[rr * g.ldo + cn] = v + g.fbias[cn];
                }
            }
        }
    }
}

// ---------------------------------------------------------------------------
// Attention: per block b, stage k[b] in LDS, loop t: scores -> softmax -> attended.
// ---------------------------------------------------------------------------
__global__ __launch_bounds__(256) void attn_kernel(const ushort_t* q, const ushort_t* kmat,
                                                   const ushort_t* meta, const int* inp,
                                                   ushort_t* att) {
    int b = blockIdx.x;
    __shared__ __attribute__((aligned(16))) ushort_t klds[L_DIM * 264];
    __shared__ float qlds[256];
    __shared__ float sc[L_DIM];
    __shared__ int msk[L_DIM];
    __shared__ float inv_s;
    int tid = threadIdx.x;

    for (int idx = tid; idx < L_DIM * 32; idx += 256) {
        int r = idx >> 5, c8 = (idx & 31) * 8;
        *(uint4*)&klds[r * 264 + c8] = *(const uint4*)&kmat[((long)b * L_DIM + r) * 256 + c8];
    }
    if (tid < L_DIM) msk[tid] = inp[b * L_DIM + tid];

    for (int t = 0; t < T_DIM; t++) {
        __syncthreads();
        qlds[tid] = bf2f(q[((long)t * B_DIM + b) * 256 + tid]);
        __syncthreads();
        if (tid < 2 * L_DIM) {
            int l = tid >> 1, half = tid & 1;
            const ushort_t* kr = &klds[l * 264 + half * 128];
            const float* qp = &qlds[half * 128];
            float s = 0.f;
            for (int j = 0; j < 128; j++) s += qp[j] * bf2f(kr[j]);
            s += __shfl_xor(s, 1);
            if (half == 0) sc[l] = (msk[l] == 0) ? -1000000000.0f : s * 0.0625f;
        }
        __syncthreads();
        if (tid < 64) {
            float s1 = sc[tid];
            float s2 = (tid + 64 < L_DIM) ? sc[tid + 64] : -1e30f;
            float mx = fmaxf(s1, s2);
            for (int o = 1; o < 64; o <<= 1) mx = fmaxf(mx, __shfl_xor(mx, o));
            float e1 = __expf(s1 - mx);
            float e2 = (tid + 64 < L_DIM) ? __expf(s2 - mx) : 0.f;
            float tot = e1 + e2;
            for (int o = 1; o < 64; o <<= 1) tot += __shfl_xor(tot, o);
            sc[tid] = e1;
            if (tid + 64 < L_DIM) sc[tid + 64] = e2;
            if (tid == 0) inv_s = 1.0f / tot;
        }
        __syncthreads();
        float a = 0.f;
        const ushort_t* mb = &meta[(long)b * L_DIM * 256 + tid];
        for (int l = 0; l < L_DIM; l++) a += sc[l] * bf2f(mb[(long)l * 256]);
        a *= inv_s;
        att[((long)t * B_DIM + b) * 256 + tid] = f2bf(a);
    }
}

// ---------------------------------------------------------------------------
// Precompute C[kind,k] = Wd[kind][k] (512x256) @ Wz[kind][k*256:..] (256x256) -> bf16 (6144 x 256)
// ---------------------------------------------------------------------------
__global__ __launch_bounds__(256) void call_precompute(const ushort_t* Wdh, const ushort_t* Wdx,
                                                       const ushort_t* Wdb, const ushort_t* Wzh,
                                                       const ushort_t* Wzx, const ushort_t* Wzb,
                                                       ushort_t* Call) {
    int bk = blockIdx.x;            // kind*4 + k
    int kind = bk >> 2, kk = bk & 3;
    int h0 = blockIdx.y * 64;
    int m0 = blockIdx.z * 64;
    const ushort_t* Wd = (kind == 0) ? Wdh : ((kind == 1) ? Wdx : Wdb);
    const ushort_t* Wz = (kind == 0) ? Wzh : ((kind == 1) ? Wzx : Wzb);
    __shared__ __attribute__((aligned(16))) ushort_t dt[64 * 72];
    __shared__ __attribute__((aligned(16))) ushort_t zt[64 * 72];
    int tid = threadIdx.x;
    int ty = tid >> 4, tx = tid & 15;
    float acc[4][4] = {};
    for (int z0 = 0; z0 < 256; z0 += 64) {
        __syncthreads();
        for (int idx = tid; idx < 512; idx += 256) {
            int r = idx >> 3, c8 = (idx & 7) * 8;
            *(uint4*)&dt[r * 72 + c8] = *(const uint4*)&Wd[((long)(kk * 512 + h0 + r)) * 256 + z0 + c8];
            *(uint4*)&zt[r * 72 + c8] = *(const uint4*)&Wz[((long)(kk * 256 + z0 + r)) * 256 + m0 + c8];
        }
        __syncthreads();
        for (int z = 0; z < 64; z++) {
            float a[4], bb[4];
#pragma unroll
            for (int i = 0; i < 4; i++) a[i] = bf2f(dt[(ty * 4 + i) * 72 + z]);
#pragma unroll
            for (int j = 0; j < 4; j++) bb[j] = bf2f(zt[z * 72 + tx * 4 + j]);
#pragma unroll
            for (int i = 0; i < 4; i++)
#pragma unroll
                for (int j = 0; j < 4; j++) acc[i][j] += a[i] * bb[j];
        }
    }
#pragma unroll
    for (int i = 0; i < 4; i++)
#pragma unroll
        for (int j = 0; j < 4; j++)
            Call[((long)(kind * 2048 + kk * 512 + h0 + ty * 4 + i)) * 256 + m0 + tx * 4 + j] = f2bf(acc[i][j]);
}

// dbias[n]: kind 0 -> Wdh[k,h,:]·bzh_k ; kind 1 -> Wdx·bzx ; kind 2 -> bdb[k,h]
__global__ __launch_bounds__(256) void dbias_kernel(const ushort_t* Wdh, const ushort_t* Wdx,
                                                    const ushort_t* bzh, const ushort_t* bzx,
                                                    const ushort_t* bdb, float* dbias) {
    int n = blockIdx.x * 256 + threadIdx.x;  // 0..6143
    int kind = n >> 11, kk = (n >> 9) & 3, h = n & 511;
    float s = 0.f;
    if (kind == 2) {
        s = bf2f(bdb[kk * 512 + h]);
    } else {
        const ushort_t* Wd = (kind == 0) ? Wdh : Wdx;
        const ushort_t* bz = (kind == 0) ? bzh : bzx;
        for (int z = 0; z < 256; z++)
            s += bf2f(Wd[((long)(kk * 512 + h)) * 256 + z]) * bf2f(bz[kk * 256 + z]);
    }
    dbias[n] = s;
}

// ---------------------------------------------------------------------------
// Per-step elementwise: y = d_h*wh + d_x*wx + d_b, LayerNorm per (b,k), gates, LSTM.
// Flag-aware output writes (f32 world vs bf16 world).
// ---------------------------------------------------------------------------
__global__ __launch_bounds__(256) void step_elem(const float* dall, const float* wh,
                                                 const ushort_t* wx, float* c, ushort_t* hbf,
                                                 const ushort_t* ln_g, const ushort_t* ln_b,
                                                 void* outbase, long off_t, int last,
                                                 const int* flagp) {
    int b = blockIdx.x, tid = threadIdx.x;
    int w = tid >> 6, lane = tid & 63;
    __shared__ float yln[4 * 512];
    const float* db = dall + (long)b * 6144;
    const float* whb = wh + (long)b * 2048;
    const ushort_t* wxb = wx + (long)b * 2048;
    float y[8];
    float sum = 0.f, ss = 0.f;
#pragma unroll
    for (int j = 0; j < 8; j++) {
        int h = lane + j * 64;
        int n = w * 512 + h;
        float v = db[n] * whb[n] + db[2048 + n] * bf2f(wxb[n]) + db[4096 + n];
        v = fixf(v);
        y[j] = v;
        sum += v;
        ss += v * v;
    }
    for (int o = 1; o < 64; o <<= 1) {
        sum += __shfl_xor(sum, o);
        ss += __shfl_xor(ss, o);
    }
    float mu = sum * (1.f / 512.f);
    float var = ss * (1.f / 512.f) - mu * mu;
    float rstd = rsqrtf(fmaxf(var, 0.f) + 1e-5f);
#pragma unroll
    for (int j = 0; j < 8; j++) {
        int h = lane + j * 64;
        float g = bf2f(ln_g[w * 512 + h]);
        float bb = bf2f(ln_b[w * 512 + h]);
        yln[w * 512 + h] = (y[j] - mu) * rstd * g + bb;
    }
    __syncthreads();
    int f = *flagp;
#pragma unroll
    for (int s = 0; s < 2; s++) {
        int h = tid + s * 256;
        float iv = yln[h], fv = yln[512 + h], gv = yln[1024 + h], ov = yln[1536 + h];
        long ci = (long)b * 512 + h;
        float cold = c[ci];
        float cn = sigmoidf_(fv) * cold + sigmoidf_(iv) * tanhf(gv);
        float hn = sigmoidf_(ov) * tanhf(cn);
        c[ci] = cn;
        hbf[ci] = f2bf(hn);
        if (f) {
            float* of = (float*)outbase;
            of[off_t + ci] = hn;
            if (last) { of[33554432 + ci] = hn; of[33816576 + ci] = cn; }
        } else {
            ushort_t* ob = (ushort_t*)outbase;
            ob[off_t + ci] = f2bf(hn);
            if (last) { ob[33554432 + ci] = f2bf(hn); ob[33816576 + ci] = f2bf(cn); }
        }
    }
}

// ---------------------------------------------------------------------------
extern "C" void kernel_launch(void* const* d_in, const int* in_sizes, int n_in,
                              void* d_out, int out_size, void* d_ws, size_t ws_size,
                              hipStream_t stream) {
    const int* inp = (const int*)d_in[2];

    size_t off = 0;
    char* wsb = (char*)d_ws;
    auto alloc = [&](size_t bytes) -> void* {
        off = (off + 255) & ~(size_t)255;
        void* p = wsb + off;
        off += bytes;
        return p;
    };

    int* flagp = (int*)alloc(256);

    // canonical bf16 copies of all 21 float tensors (skip inp at index 2)
    static const int fidx[21] = {0,1,3,4,5,6,7,8,9,10,11,12,13,14,15,16,17,18,19,20,21};
    IngestP ip{};
    long total = 0;
    ushort_t* canon[21];
    for (int t = 0; t < 21; t++) {
        int src_i = fidx[t];
        int n = in_sizes[src_i];
        canon[t] = (ushort_t*)alloc((size_t)n * 2);
        ip.src[t] = d_in[src_i];
        ip.dst[t] = canon[t];
        ip.n[t] = n;
        total += n;
    }
    ip.total = total;
    ip.flag = flagp;

    const ushort_t* x    = canon[0];
    const ushort_t* meta = canon[1];
    const ushort_t* Wq   = canon[2];
    const ushort_t* bq   = canon[3];
    const ushort_t* Wk   = canon[4];
    const ushort_t* bk   = canon[5];
    const ushort_t* Wm   = canon[6];
    const ushort_t* bm   = canon[7];
    const ushort_t* Wzh  = canon[8];
    const ushort_t* bzh  = canon[9];
    const ushort_t* Wzx  = canon[10];
    const ushort_t* bzx  = canon[11];
    const ushort_t* Wzb  = canon[12];
    const ushort_t* Wdh  = canon[13];
    const ushort_t* Wdx  = canon[14];
    const ushort_t* Wdb  = canon[15];
    const ushort_t* bdb  = canon[16];
    const ushort_t* w_h  = canon[17];
    const ushort_t* w_x  = canon[18];
    const ushort_t* ln_g = canon[19];
    const ushort_t* ln_b = canon[20];

    ushort_t* qb    = (ushort_t*)alloc(33554432);   // 65536 x 256 bf16
    ushort_t* kmb   = (ushort_t*)alloc(26214400);   // 51200 x 256 bf16
    ushort_t* attb  = (ushort_t*)alloc(33554432);   // 65536 x 256 bf16
    ushort_t* preb  = (ushort_t*)alloc(33554432);   // 65536 x 256 bf16
    ushort_t* callb = (ushort_t*)alloc(3145728);    // 6144 x 256 bf16
    float*    dbias = (float*)alloc(24576);         // 6144 f32
    ushort_t* hbf   = (ushort_t*)alloc(524288);     // 512 x 512 bf16
    float*    cf    = (float*)alloc(1048576);       // 512 x 512 f32
    ushort_t* mgd   = (ushort_t*)alloc(262144);     // 512 x 256 bf16
    float*    whf   = (float*)alloc(4194304);       // 512 x 2048 f32
    float*    dall  = (float*)alloc(12582912);      // 512 x 6144 f32
    size_t base_end = (off + 255) & ~(size_t)255;
    bool full = (base_end + 268435456ull) <= ws_size;
    ushort_t* wxb = (ushort_t*)alloc(full ? 268435456ull : 2097152ull);

    // dtype detect + ingest + init
    detect_kernel<<<dim3(1), 256, 0, stream>>>((const ushort_t*)d_in[0], 262144, flagp);
    ingest_all<<<dim3(2048), 256, 0, stream>>>(ip);
    zero_hhat<<<dim3(1024), 256, 0, stream>>>(d_out, flagp);
    hipMemsetAsync(hbf, 0, 524288, stream);
    hipMemsetAsync(cf, 0, 1048576, stream);

    const int BIG = 1 << 30;

    // A1: kmat = meta @ Wk^T + bk   (51200 x 256, K=256)
    {
        GP g{};
        g.A1 = meta; g.lda1 = 256; g.K1 = BIG; g.A2 = meta; g.lda2 = 256;
        g.W1 = Wk; g.ldw1 = 256; g.wc1 = 0; g.Nsplit = BIG; g.W2 = Wk; g.ldw2 = 256; g.wc2 = 0;
        g.K = 256; g.mode = 0; g.bias = bk; g.outb = kmb; g.ldo = 256;
        gemm_bt<<<dim3(400, 2), 256, 0, stream>>>(g);
    }
    // A2: q = x @ Wq^T + bq   (65536 x 256, K=512)
    {
        GP g{};
        g.A1 = x; g.lda1 = 512; g.K1 = BIG; g.A2 = x; g.lda2 = 512;
        g.W1 = Wq; g.ldw1 = 512; g.wc1 = 0; g.Nsplit = BIG; g.W2 = Wq; g.ldw2 = 512; g.wc2 = 0;
        g.K = 512; g.mode = 0; g.bias = bq; g.outb = qb; g.ldo = 256;
        gemm_bt<<<dim3(512, 2), 256, 0, stream>>>(g);
    }
    // A3: attention -> attb
    attn_kernel<<<dim3(512), 256, 0, stream>>>(qb, kmb, meta, inp, attb);
    // A4: pre_merged = [x, att] @ Wm[:, :768]^T + bm   (65536 x 256, K=768)
    {
        GP g{};
        g.A1 = x; g.lda1 = 512; g.K1 = 512; g.A2 = attb; g.lda2 = 256;
        g.W1 = Wm; g.ldw1 = 1280; g.wc1 = 0; g.Nsplit = BIG; g.W2 = Wm; g.ldw2 = 1280; g.wc2 = 0;
        g.K = 768; g.mode = 0; g.bias = bm; g.outb = preb; g.ldo = 256;
        gemm_bt<<<dim3(512, 2), 256, 0, stream>>>(g);
    }
    // A5: wx_all = x @ w_x^T   (65536 x 2048, K=512) — only if workspace allows
    if (full) {
        GP g{};
        g.A1 = x; g.lda1 = 512; g.K1 = BIG; g.A2 = x; g.lda2 = 512;
        g.W1 = w_x; g.ldw1 = 512; g.wc1 = 0; g.Nsplit = BIG; g.W2 = w_x; g.ldw2 = 512; g.wc2 = 0;
        g.K = 512; g.mode = 0; g.bias = nullptr; g.outb = wxb; g.ldo = 2048;
        gemm_bt<<<dim3(512, 16), 256, 0, stream>>>(g);
    }
    // P1/P2: combined d-matrices and bias
    call_precompute<<<dim3(12, 8, 4), 256, 0, stream>>>(Wdh, Wdx, Wdb, Wzh, Wzx, Wzb, callb);
    dbias_kernel<<<dim3(24), 256, 0, stream>>>(Wdh, Wdx, bzh, bzx, bdb, dbias);

    // Sequential scan
    for (int t = 0; t < T_DIM; t++) {
        if (!full) {
            GP g{};
            g.A1 = x + (long)t * B_DIM * DIN; g.lda1 = 512; g.K1 = BIG; g.A2 = g.A1; g.lda2 = 512;
            g.W1 = w_x; g.ldw1 = 512; g.wc1 = 0; g.Nsplit = BIG; g.W2 = w_x; g.ldw2 = 512; g.wc2 = 0;
            g.K = 512; g.mode = 0; g.bias = nullptr; g.outb = wxb; g.ldo = 2048;
            gemm_bt<<<dim3(4, 16), 256, 0, stream>>>(g);
        }
        // K12: [merged | wh] = h @ [Wm[:,768:] ; w_h]^T   (512 x 2304, K=512)
        {
            GP g{};
            g.A1 = hbf; g.lda1 = 512; g.K1 = BIG; g.A2 = hbf; g.lda2 = 512;
            g.W1 = Wm; g.ldw1 = 1280; g.wc1 = 768; g.Nsplit = 256;
            g.W2 = w_h; g.ldw2 = 512; g.wc2 = 0;
            g.K = 512; g.mode = 1;
            g.pre = preb + (long)t * B_DIM * 256; g.merged = mgd; g.wh = whf;
            gemm_bt<<<dim3(4, 18), 256, 0, stream>>>(g);
        }
        // K3: dall = merged @ C^T + dbias   (512 x 6144, K=256)
        {
            GP g{};
            g.A1 = mgd; g.lda1 = 256; g.K1 = BIG; g.A2 = mgd; g.lda2 = 256;
            g.W1 = callb; g.ldw1 = 256; g.wc1 = 0; g.Nsplit = BIG; g.W2 = callb; g.ldw2 = 256; g.wc2 = 0;
            g.K = 256; g.mode = 2; g.outf = dall; g.ldo = 6144; g.fbias = dbias;
            gemm_bt<<<dim3(4, 48), 256, 0, stream>>>(g);
        }
        // K4: elementwise + LN + LSTM update
        const ushort_t* wxt = full ? (wxb + (long)t * B_DIM * 2048) : wxb;
        step_elem<<<dim3(512), 256, 0, stream>>>(dall, whf, wxt, cf, hbf, ln_g, ln_b,
                                                 d_out, (long)t * B_DIM * H_DIM,
                                                 (t == T_DIM - 1) ? 1 : 0, flagp);
    }
}